// Round 1
// baseline (505.619 us; speedup 1.0000x reference)
//
#include <hip/hip_runtime.h>

#define NN 4
#define CC 256
#define HH 128
#define FWBv 16
#define BLK 8
#define NBBOX 100
#define MM (NBBOX * NN * FWBv * FWBv)  // 102400

typedef __attribute__((ext_vector_type(8))) short bf16x8;
typedef __attribute__((ext_vector_type(4))) float f32x4;

__device__ __forceinline__ unsigned short f2bf(float x) {
  union { float f; unsigned int u; } v; v.f = x;
  unsigned int r = v.u + 0x7FFFu + ((v.u >> 16) & 1u);
  return (unsigned short)(r >> 16);
}

// ---------------- Kernel 0: weight fp32 -> bf16 ----------------
__global__ __launch_bounds__(256) void k_convert(
    const float* __restrict__ Wf, const float* __restrict__ Ww,
    const float* __restrict__ Wpw,
    unsigned short* __restrict__ oWf, unsigned short* __restrict__ oWw,
    unsigned short* __restrict__ oWpw) {
  int i = blockIdx.x * 256 + threadIdx.x;  // grid = 256 blocks -> i < 65536
  oWf[i] = f2bf(Wf[i]);
  oWw[i] = f2bf(Ww[i]);
  if (i < 64 * 256) oWpw[i] = f2bf(Wpw[i]);
}

// 64-row x-tile GEMM pass over K=256, N covered by 4 waves * 64 cols
__device__ __forceinline__ void gemm_k256(
    const unsigned short (*xs)[264], const unsigned short* __restrict__ B,
    int w, int lr, int quad, f32x4 acc[4][4]) {
#pragma unroll
  for (int kt = 0; kt < 8; ++kt) {
    const int kk = kt * 32 + quad * 8;
    bf16x8 a[4], b[4];
#pragma unroll
    for (int mt = 0; mt < 4; ++mt)
      a[mt] = *(const bf16x8*)&xs[mt * 16 + lr][kk];
#pragma unroll
    for (int nt = 0; nt < 4; ++nt)
      b[nt] = *(const bf16x8*)(B + (size_t)(w * 64 + nt * 16 + lr) * 256 + kk);
#pragma unroll
    for (int mt = 0; mt < 4; ++mt)
#pragma unroll
      for (int nt = 0; nt < 4; ++nt)
        acc[mt][nt] = __builtin_amdgcn_mfma_f32_16x16x32_bf16(
            a[mt], b[nt], acc[mt][nt], 0, 0, 0);
  }
}

// ---------------- Kernel 1: feat_f, feat_w, point_weight ----------------
// grid = MM/64 blocks, 256 threads (4 waves). Each block: 64 rows of x.
__global__ __launch_bounds__(256) void k1(
    const float* __restrict__ rois,
    const unsigned short* __restrict__ Wf,   // bf16 [256][256]
    const unsigned short* __restrict__ Ww,   // bf16 [256][256]
    const unsigned short* __restrict__ Wpw,  // bf16 [64][256]
    const float* __restrict__ bf_, const float* __restrict__ bw_,
    const float* __restrict__ bpw_,
    float* __restrict__ fused_slot,  // d_out[0 : M*256]   <- feat_f
    float* __restrict__ out_slot)    // d_out[M*256 : ]    <- pw in cols 0..63
{
  __shared__ unsigned short xs[64][264];  // x tile, later reused as feat_w tile
  const int t = threadIdx.x;
  const int lane = t & 63, w = t >> 6;
  const int lr = lane & 15, quad = lane >> 4;
  const int row_base = blockIdx.x * 64;

  // stage X: 64x256 fp32 -> bf16 LDS (coalesced float4 loads)
#pragma unroll
  for (int i = 0; i < 16; ++i) {
    const int elem = (i * 256 + t) * 4;
    const int r = elem >> 8, c = elem & 255;
    const float4 v = *(const float4*)(rois + (size_t)row_base * 256 + elem);
    unsigned int lo = f2bf(v.x) | ((unsigned int)f2bf(v.y) << 16);
    unsigned int hi = f2bf(v.z) | ((unsigned int)f2bf(v.w) << 16);
    *(uint2*)&xs[r][c] = make_uint2(lo, hi);
  }
  __syncthreads();

  // Pass A: feat_f = relu(x @ Wf^T + bf) -> fused_slot (global)
  {
    f32x4 acc[4][4];
#pragma unroll
    for (int mt = 0; mt < 4; ++mt)
#pragma unroll
      for (int nt = 0; nt < 4; ++nt) acc[mt][nt] = (f32x4){0.f, 0.f, 0.f, 0.f};
    gemm_k256(xs, Wf, w, lr, quad, acc);
#pragma unroll
    for (int nt = 0; nt < 4; ++nt) {
      const int gcol = w * 64 + nt * 16 + lr;
      const float bias = bf_[gcol];
#pragma unroll
      for (int mt = 0; mt < 4; ++mt)
#pragma unroll
        for (int r = 0; r < 4; ++r) {
          float vv = acc[mt][nt][r] + bias;
          vv = vv > 0.f ? vv : 0.f;
          fused_slot[(size_t)(row_base + mt * 16 + quad * 4 + r) * 256 + gcol] = vv;
        }
    }
  }

  // Pass B: feat_w = relu(x @ Ww^T + bw) -> bf16 back into xs (overwrites x)
  {
    f32x4 acc[4][4];
#pragma unroll
    for (int mt = 0; mt < 4; ++mt)
#pragma unroll
      for (int nt = 0; nt < 4; ++nt) acc[mt][nt] = (f32x4){0.f, 0.f, 0.f, 0.f};
    gemm_k256(xs, Ww, w, lr, quad, acc);
    __syncthreads();  // all reads of x done before overwrite
#pragma unroll
    for (int nt = 0; nt < 4; ++nt) {
      const int gcol = w * 64 + nt * 16 + lr;
      const float bias = bw_[gcol];
#pragma unroll
      for (int mt = 0; mt < 4; ++mt)
#pragma unroll
        for (int r = 0; r < 4; ++r) {
          float vv = acc[mt][nt][r] + bias;
          vv = vv > 0.f ? vv : 0.f;
          xs[mt * 16 + quad * 4 + r][gcol] = f2bf(vv);
        }
    }
    __syncthreads();
  }

  // Pass C: pw = feat_w @ Wpw^T + bpw  (64 rows x 64 cols), wave w -> cols 16w..16w+15
  {
    f32x4 acc2[4];
#pragma unroll
    for (int mt = 0; mt < 4; ++mt) acc2[mt] = (f32x4){0.f, 0.f, 0.f, 0.f};
#pragma unroll
    for (int kt = 0; kt < 8; ++kt) {
      const int kk = kt * 32 + quad * 8;
      const bf16x8 b = *(const bf16x8*)(Wpw + (size_t)(w * 16 + lr) * 256 + kk);
#pragma unroll
      for (int mt = 0; mt < 4; ++mt) {
        const bf16x8 a = *(const bf16x8*)&xs[mt * 16 + lr][kk];
        acc2[mt] = __builtin_amdgcn_mfma_f32_16x16x32_bf16(a, b, acc2[mt], 0, 0, 0);
      }
    }
    const int j = w * 16 + lr;
    const float bias = bpw_[j];
#pragma unroll
    for (int mt = 0; mt < 4; ++mt)
#pragma unroll
      for (int r = 0; r < 4; ++r)
        out_slot[(size_t)(row_base + mt * 16 + quad * 4 + r) * 256 + j] =
            acc2[mt][r] + bias;
  }
}

// ---------------- Kernel 2: einsum + fused add ----------------
// grid = 1024 blocks (one per (n,p,q)), 512 threads (8 waves).
// out[k,c] = sum_j pw[k,j] * fb[c,j];  fused = feat_f + out.
__global__ __launch_bounds__(512) void k2(
    const float* __restrict__ feature,
    float* __restrict__ fused_slot,  // holds feat_f on entry
    float* __restrict__ out_slot)    // holds pw in cols 0..63 on entry
{
  __shared__ unsigned short fbuf[256][72];  // fb[c][j] bf16
  __shared__ unsigned short pwb[112][72];   // pw[k][j] bf16, rows 100..111 zero
  const int t = threadIdx.x;
  const int lane = t & 63, w = t >> 6;
  const int lr = lane & 15, quad = lane >> 4;
  const int bid = blockIdx.x;               // base = (n*16+p)*16+q == bid
  const int n = bid >> 8, p = (bid >> 4) & 15, q = bid & 15;

  // zero pad rows k=100..111 (12 rows x 72 ushort = 432 uints), disjoint from loads
  if (t < 432) {
    const int r = 100 + t / 36, cw = t % 36;
    *(unsigned int*)&pwb[r][cw * 2] = 0u;
  }

  // stage feature block: (c,a) pairs, 8 contiguous floats each
  for (int pi = t; pi < 2048; pi += 512) {
    const int c = pi >> 3, a = pi & 7;
    const float* fp =
        feature + (((size_t)n * 256 + c) * 128 + p * 8 + a) * 128 + q * 8;
    const float4 v0 = *(const float4*)fp;
    const float4 v1 = *(const float4*)(fp + 4);
    unsigned int u0 = f2bf(v0.x) | ((unsigned int)f2bf(v0.y) << 16);
    unsigned int u1 = f2bf(v0.z) | ((unsigned int)f2bf(v0.w) << 16);
    unsigned int u2 = f2bf(v1.x) | ((unsigned int)f2bf(v1.y) << 16);
    unsigned int u3 = f2bf(v1.z) | ((unsigned int)f2bf(v1.w) << 16);
    *(uint4*)&fbuf[c][a * 8] = make_uint4(u0, u1, u2, u3);
  }

  // stage pw rows: k = 0..99, 64 fp32 each from out_slot cols 0..63
  for (int pi = t; pi < 1600; pi += 512) {
    const int k = pi >> 4, ch = pi & 15;
    const float4 v =
        *(const float4*)(out_slot + (size_t)(bid + k * 1024) * 256 + ch * 4);
    unsigned int lo = f2bf(v.x) | ((unsigned int)f2bf(v.y) << 16);
    unsigned int hi = f2bf(v.z) | ((unsigned int)f2bf(v.w) << 16);
    *(uint2*)&pwb[k][ch * 4] = make_uint2(lo, hi);
  }
  __syncthreads();

  // GEMM: (112 x 64) @ (64 x 256), wave w -> cols 32w..32w+31
  f32x4 acc[7][2];
#pragma unroll
  for (int mt = 0; mt < 7; ++mt)
#pragma unroll
    for (int nt = 0; nt < 2; ++nt) acc[mt][nt] = (f32x4){0.f, 0.f, 0.f, 0.f};
#pragma unroll
  for (int kt = 0; kt < 2; ++kt) {
    const int kk = kt * 32 + quad * 8;
    bf16x8 a[7], b[2];
#pragma unroll
    for (int mt = 0; mt < 7; ++mt)
      a[mt] = *(const bf16x8*)&pwb[mt * 16 + lr][kk];
#pragma unroll
    for (int nt = 0; nt < 2; ++nt)
      b[nt] = *(const bf16x8*)&fbuf[w * 32 + nt * 16 + lr][kk];
#pragma unroll
    for (int mt = 0; mt < 7; ++mt)
#pragma unroll
      for (int nt = 0; nt < 2; ++nt)
        acc[mt][nt] =
            __builtin_amdgcn_mfma_f32_16x16x32_bf16(a[mt], b[nt], acc[mt][nt], 0, 0, 0);
  }

  // epilogue: write out + fused (= feat_f + out)
#pragma unroll
  for (int mt = 0; mt < 7; ++mt) {
#pragma unroll
    for (int r = 0; r < 4; ++r) {
      const int k = mt * 16 + quad * 4 + r;
      if (k < 100) {
        const size_t rowoff = (size_t)(bid + k * 1024) * 256;
#pragma unroll
        for (int nt = 0; nt < 2; ++nt) {
          const int c = w * 32 + nt * 16 + lr;
          const float val = acc[mt][nt][r];
          out_slot[rowoff + c] = val;
          fused_slot[rowoff + c] = fused_slot[rowoff + c] + val;
        }
      }
    }
  }
}

extern "C" void kernel_launch(void* const* d_in, const int* in_sizes, int n_in,
                              void* d_out, int out_size, void* d_ws, size_t ws_size,
                              hipStream_t stream) {
  const float* feature = (const float*)d_in[0];
  const float* rois = (const float*)d_in[1];
  const float* Ww = (const float*)d_in[2];
  const float* bw = (const float*)d_in[3];
  const float* Wf = (const float*)d_in[4];
  const float* bfv = (const float*)d_in[5];
  const float* Wpw = (const float*)d_in[6];
  const float* bpw = (const float*)d_in[7];

  unsigned short* wsWf = (unsigned short*)d_ws;       // 65536 bf16
  unsigned short* wsWw = wsWf + 256 * 256;            // 65536 bf16
  unsigned short* wsWpw = wsWw + 256 * 256;           // 16384 bf16  (total 288 KB)

  float* fused_slot = (float*)d_out;
  float* out_slot = fused_slot + (size_t)MM * 256;

  k_convert<<<256, 256, 0, stream>>>(Wf, Ww, Wpw, wsWf, wsWw, wsWpw);
  k1<<<MM / 64, 256, 0, stream>>>(rois, wsWf, wsWw, wsWpw, bfv, bw, bpw,
                                  fused_slot, out_slot);
  k2<<<NN * FWBv * FWBv, 512, 0, stream>>>(feature, fused_slot, out_slot);
}

// Round 3
// 504.841 us; speedup vs baseline: 1.0015x; 1.0015x over previous
//
#include <hip/hip_runtime.h>

#define NN 4
#define CC 256
#define HH 128
#define FWBv 16
#define BLK 8
#define NBBOX 100
#define MM (NBBOX * NN * FWBv * FWBv)  // 102400

typedef __attribute__((ext_vector_type(8))) short bf16x8;
typedef __attribute__((ext_vector_type(4))) float f32x4;

__device__ __forceinline__ unsigned short f2bf(float x) {
  union { float f; unsigned int u; } v; v.f = x;
  unsigned int r = v.u + 0x7FFFu + ((v.u >> 16) & 1u);
  return (unsigned short)(r >> 16);
}

// async global->LDS, 16B per lane; LDS dest = wave-uniform base + lane*16
__device__ __forceinline__ void async16(const void* g, void* l) {
  __builtin_amdgcn_global_load_lds(
      (__attribute__((address_space(1))) void*)(g),
      (__attribute__((address_space(3))) void*)(l), 16, 0, 0);
}

// ---------------- Kernel 0: weight fp32 -> bf16 ----------------
__global__ __launch_bounds__(256) void k_convert(
    const float* __restrict__ Wf, const float* __restrict__ Ww,
    const float* __restrict__ Wpw,
    unsigned short* __restrict__ oWf, unsigned short* __restrict__ oWw,
    unsigned short* __restrict__ oWpw) {
  int i = blockIdx.x * 256 + threadIdx.x;  // grid = 256 blocks -> i < 65536
  oWf[i] = f2bf(Wf[i]);
  oWw[i] = f2bf(Ww[i]);
  if (i < 64 * 256) oWpw[i] = f2bf(Wpw[i]);
}

// ---------------- Kernel 1: feat_f, feat_w, point_weight ----------------
// grid = MM/64 blocks, 256 threads (4 waves). Each block: 64 rows of x.
// B staged into LDS in BK=64 chunks via global_load_lds (m97 structure).
__global__ __launch_bounds__(256) void k1(
    const float* __restrict__ rois,
    const unsigned short* __restrict__ Wf,   // bf16 [256][256]
    const unsigned short* __restrict__ Ww,   // bf16 [256][256]
    const unsigned short* __restrict__ Wpw,  // bf16 [64][256]
    const float* __restrict__ bf_, const float* __restrict__ bw_,
    const float* __restrict__ bpw_,
    float* __restrict__ fused_slot,  // d_out[0 : M*256]   <- feat_f
    float* __restrict__ out_slot)    // d_out[M*256 : ]    <- pw in cols 0..63
{
  __shared__ unsigned short xs[64][264];   // x tile (later feat_w tile), 33.8 KB
  __shared__ unsigned short bs[256 * 64];  // B chunk [256 rows][64 k], 32 KB, no pad
  const int t = threadIdx.x;
  const int lane = t & 63, w = t >> 6;
  const int lr = lane & 15, quad = lane >> 4;
  const int row_base = blockIdx.x * 64;

  // stage X: 64x256 fp32 -> bf16 LDS (coalesced float4 loads)
#pragma unroll
  for (int i = 0; i < 16; ++i) {
    const int elem = (i * 256 + t) * 4;
    const int r = elem >> 8, c = elem & 255;
    const float4 v = *(const float4*)(rois + (size_t)row_base * 256 + elem);
    unsigned int lo = f2bf(v.x) | ((unsigned int)f2bf(v.y) << 16);
    unsigned int hi = f2bf(v.z) | ((unsigned int)f2bf(v.w) << 16);
    *(uint2*)&xs[r][c] = make_uint2(lo, hi);
  }

  // Pass A (Wf -> feat_f to global) and Pass B (Ww -> feat_w back into xs)
  for (int pass = 0; pass < 2; ++pass) {
    const unsigned short* Wp = pass ? Ww : Wf;
    f32x4 acc[4][4];
#pragma unroll
    for (int mt = 0; mt < 4; ++mt)
#pragma unroll
      for (int nt = 0; nt < 4; ++nt) acc[mt][nt] = (f32x4){0.f, 0.f, 0.f, 0.f};

    for (int kc = 0; kc < 4; ++kc) {
      __syncthreads();  // prev readers of bs done (and xs visible on first iter)
      // stage B chunk: rows 0..255 x k [kc*64, kc*64+64) -> bs[row*64 + k]
#pragma unroll
      for (int i = 0; i < 8; ++i) {
        const int r0 = i * 32 + w * 8;  // wave-uniform
        const unsigned short* g =
            Wp + (size_t)(r0 + (lane >> 3)) * 256 + kc * 64 + (lane & 7) * 8;
        async16(g, &bs[r0 * 64]);
      }
      __syncthreads();
#pragma unroll
      for (int kt = 0; kt < 2; ++kt) {
        const int kk = kt * 32 + quad * 8;
        bf16x8 a[4], b[4];
#pragma unroll
        for (int mt = 0; mt < 4; ++mt)
          a[mt] = *(const bf16x8*)&xs[mt * 16 + lr][kc * 64 + kk];
#pragma unroll
        for (int nt = 0; nt < 4; ++nt)
          b[nt] = *(const bf16x8*)&bs[(w * 64 + nt * 16 + lr) * 64 + kk];
#pragma unroll
        for (int mt = 0; mt < 4; ++mt)
#pragma unroll
          for (int nt = 0; nt < 4; ++nt)
            acc[mt][nt] = __builtin_amdgcn_mfma_f32_16x16x32_bf16(
                a[mt], b[nt], acc[mt][nt], 0, 0, 0);
      }
    }

    if (pass == 0) {
      // epilogue A: feat_f = relu(acc + bias) -> fused_slot
#pragma unroll
      for (int nt = 0; nt < 4; ++nt) {
        const int gcol = w * 64 + nt * 16 + lr;
        const float bias = bf_[gcol];
#pragma unroll
        for (int mt = 0; mt < 4; ++mt)
#pragma unroll
          for (int r = 0; r < 4; ++r) {
            float vv = acc[mt][nt][r] + bias;
            vv = vv > 0.f ? vv : 0.f;
            fused_slot[(size_t)(row_base + mt * 16 + quad * 4 + r) * 256 + gcol] = vv;
          }
      }
    } else {
      // epilogue B: feat_w = relu(acc + bias) -> bf16 back into xs
      __syncthreads();  // all MFMA reads of xs done before overwrite
#pragma unroll
      for (int nt = 0; nt < 4; ++nt) {
        const int gcol = w * 64 + nt * 16 + lr;
        const float bias = bw_[gcol];
#pragma unroll
        for (int mt = 0; mt < 4; ++mt)
#pragma unroll
          for (int r = 0; r < 4; ++r) {
            float vv = acc[mt][nt][r] + bias;
            vv = vv > 0.f ? vv : 0.f;
            xs[mt * 16 + quad * 4 + r][gcol] = f2bf(vv);
          }
      }
    }
  }

  // Pass C: pw = feat_w @ Wpw^T + bpw (64x64), wave w -> cols 16w..16w+15
  {
    // stage all of Wpw (64x256 bf16 = 32 KB = 16384 ushorts) into bs, flat copy.
    // Each wave-level async16 covers 64 lanes * 8 ushorts = 512 ushorts
    // -> need 32 wave-copies: 8 iters x 4 waves.  (R2 bug: strode by 2048.)
#pragma unroll
    for (int i = 0; i < 8; ++i) {
      const int off = (i * 4 + w) * 512;  // ushort units, wave-uniform
      async16((const void*)(Wpw + off + lane * 8), &bs[off]);
    }
    __syncthreads();  // bs staged AND xs(feat_w) visible

    f32x4 acc2[4];
#pragma unroll
    for (int mt = 0; mt < 4; ++mt) acc2[mt] = (f32x4){0.f, 0.f, 0.f, 0.f};
#pragma unroll
    for (int kt = 0; kt < 8; ++kt) {
      const int kk = kt * 32 + quad * 8;
      const bf16x8 b = *(const bf16x8*)&bs[(w * 16 + lr) * 256 + kk];
#pragma unroll
      for (int mt = 0; mt < 4; ++mt) {
        const bf16x8 a = *(const bf16x8*)&xs[mt * 16 + lr][kk];
        acc2[mt] = __builtin_amdgcn_mfma_f32_16x16x32_bf16(a, b, acc2[mt], 0, 0, 0);
      }
    }
    const int j = w * 16 + lr;
    const float bias = bpw_[j];
#pragma unroll
    for (int mt = 0; mt < 4; ++mt)
#pragma unroll
      for (int r = 0; r < 4; ++r)
        out_slot[(size_t)(row_base + mt * 16 + quad * 4 + r) * 256 + j] =
            acc2[mt][r] + bias;
  }
}

// ---------------- Kernel 2: einsum + fused add ----------------
// grid = 1024 blocks (one per (n,p,q)), 512 threads (8 waves).
// out[k,c] = sum_j pw[k,j] * fb[c,j];  fused = feat_f + out.
__global__ __launch_bounds__(512) void k2(
    const float* __restrict__ feature,
    float* __restrict__ fused_slot,  // holds feat_f on entry
    float* __restrict__ out_slot)    // holds pw in cols 0..63 on entry
{
  __shared__ unsigned short fbuf[256][72];  // fb[c][j] bf16
  __shared__ unsigned short pwb[112][72];   // pw[k][j] bf16, rows 100..111 zero
  const int t = threadIdx.x;
  const int lane = t & 63, w = t >> 6;
  const int lr = lane & 15, quad = lane >> 4;
  const int bid = blockIdx.x;               // base = (n*16+p)*16+q == bid
  const int n = bid >> 8, p = (bid >> 4) & 15, q = bid & 15;

  // zero pad rows k=100..111 (12 rows x 72 ushort = 432 uints), disjoint from loads
  if (t < 432) {
    const int r = 100 + t / 36, cw = t % 36;
    *(unsigned int*)&pwb[r][cw * 2] = 0u;
  }

  // stage feature block: (c,a) pairs, 8 contiguous floats each
  for (int pi = t; pi < 2048; pi += 512) {
    const int c = pi >> 3, a = pi & 7;
    const float* fp =
        feature + (((size_t)n * 256 + c) * 128 + p * 8 + a) * 128 + q * 8;
    const float4 v0 = *(const float4*)fp;
    const float4 v1 = *(const float4*)(fp + 4);
    unsigned int u0 = f2bf(v0.x) | ((unsigned int)f2bf(v0.y) << 16);
    unsigned int u1 = f2bf(v0.z) | ((unsigned int)f2bf(v0.w) << 16);
    unsigned int u2 = f2bf(v1.x) | ((unsigned int)f2bf(v1.y) << 16);
    unsigned int u3 = f2bf(v1.z) | ((unsigned int)f2bf(v1.w) << 16);
    *(uint4*)&fbuf[c][a * 8] = make_uint4(u0, u1, u2, u3);
  }

  // stage pw rows: k = 0..99, 64 fp32 each from out_slot cols 0..63
  for (int pi = t; pi < 1600; pi += 512) {
    const int k = pi >> 4, ch = pi & 15;
    const float4 v =
        *(const float4*)(out_slot + (size_t)(bid + k * 1024) * 256 + ch * 4);
    unsigned int lo = f2bf(v.x) | ((unsigned int)f2bf(v.y) << 16);
    unsigned int hi = f2bf(v.z) | ((unsigned int)f2bf(v.w) << 16);
    *(uint2*)&pwb[k][ch * 4] = make_uint2(lo, hi);
  }
  __syncthreads();

  // GEMM: (112 x 64) @ (64 x 256), wave w -> cols 32w..32w+31
  f32x4 acc[7][2];
#pragma unroll
  for (int mt = 0; mt < 7; ++mt)
#pragma unroll
    for (int nt = 0; nt < 2; ++nt) acc[mt][nt] = (f32x4){0.f, 0.f, 0.f, 0.f};
#pragma unroll
  for (int kt = 0; kt < 2; ++kt) {
    const int kk = kt * 32 + quad * 8;
    bf16x8 a[7], b[2];
#pragma unroll
    for (int mt = 0; mt < 7; ++mt)
      a[mt] = *(const bf16x8*)&pwb[mt * 16 + lr][kk];
#pragma unroll
    for (int nt = 0; nt < 2; ++nt)
      b[nt] = *(const bf16x8*)&fbuf[w * 32 + nt * 16 + lr][kk];
#pragma unroll
    for (int mt = 0; mt < 7; ++mt)
#pragma unroll
      for (int nt = 0; nt < 2; ++nt)
        acc[mt][nt] =
            __builtin_amdgcn_mfma_f32_16x16x32_bf16(a[mt], b[nt], acc[mt][nt], 0, 0, 0);
  }

  // epilogue: write out + fused (= feat_f + out)
#pragma unroll
  for (int mt = 0; mt < 7; ++mt) {
#pragma unroll
    for (int r = 0; r < 4; ++r) {
      const int k = mt * 16 + quad * 4 + r;
      if (k < 100) {
        const size_t rowoff = (size_t)(bid + k * 1024) * 256;
#pragma unroll
        for (int nt = 0; nt < 2; ++nt) {
          const int c = w * 32 + nt * 16 + lr;
          const float val = acc[mt][nt][r];
          out_slot[rowoff + c] = val;
          fused_slot[rowoff + c] = fused_slot[rowoff + c] + val;
        }
      }
    }
  }
}

extern "C" void kernel_launch(void* const* d_in, const int* in_sizes, int n_in,
                              void* d_out, int out_size, void* d_ws, size_t ws_size,
                              hipStream_t stream) {
  const float* feature = (const float*)d_in[0];
  const float* rois = (const float*)d_in[1];
  const float* Ww = (const float*)d_in[2];
  const float* bw = (const float*)d_in[3];
  const float* Wf = (const float*)d_in[4];
  const float* bfv = (const float*)d_in[5];
  const float* Wpw = (const float*)d_in[6];
  const float* bpw = (const float*)d_in[7];

  unsigned short* wsWf = (unsigned short*)d_ws;       // 65536 bf16
  unsigned short* wsWw = wsWf + 256 * 256;            // 65536 bf16
  unsigned short* wsWpw = wsWw + 256 * 256;           // 16384 bf16  (total 288 KB)

  float* fused_slot = (float*)d_out;
  float* out_slot = fused_slot + (size_t)MM * 256;

  k_convert<<<256, 256, 0, stream>>>(Wf, Ww, Wpw, wsWf, wsWw, wsWpw);
  k1<<<MM / 64, 256, 0, stream>>>(rois, wsWf, wsWw, wsWpw, bfv, bw, bpw,
                                  fused_slot, out_slot);
  k2<<<NN * FWBv * FWBv, 512, 0, stream>>>(feature, fused_slot, out_slot);
}